// Round 16
// baseline (249.147 us; speedup 1.0000x reference)
//
#include <hip/hip_runtime.h>

#define BATCH 256
#define SEQ 2048
#define NT 48
#define START_TAG 46
#define END_TAG 47
#define LN2f  0.6931471805599453f

// ws layout
#define TAF16 0        // K16 A-frags exp(trans) bf16: [9][64] x 8B  = 4608
#define TBF   4608     // B-frag exp(trans) f32: [9][64] x 16B       = 9216
#define TCUM  13824    // prefix sums: int cum[257] (cum[0]=0)       = 1028
#define TSC   16384    // per-chunk log2 scales: [B][64] f32         = 64KiB
#define TW    163840   // chunk matrices M^T bf16: [B][64][48][48]

typedef float v2f __attribute__((ext_vector_type(2)));
typedef float v4f __attribute__((ext_vector_type(4)));
typedef short s16x4 __attribute__((ext_vector_type(4)));
typedef unsigned int u32;
typedef u32 u32x2 __attribute__((ext_vector_type(2)));
typedef u32 u32x4 __attribute__((ext_vector_type(4)));

__device__ __forceinline__ u32 pkbf(float a, float b) {
    u32 r;
    asm("v_cvt_pk_bf16_f32 %0, %1, %2" : "=v"(r) : "v"(a), "v"(b));
    return r;
}
__device__ __forceinline__ float bflo(u32 w) { return __builtin_bit_cast(float, w << 16); }
__device__ __forceinline__ float bfhi(u32 w) { return __builtin_bit_cast(float, w & 0xffff0000u); }

__device__ __forceinline__ float rfl(float x) {
    return __builtin_bit_cast(float,
        __builtin_amdgcn_readfirstlane(__builtin_bit_cast(int, x)));
}

__device__ __forceinline__ v4f mfma16_z(s16x4 a, s16x4 b, v4f z) {
    v4f d;
    asm volatile("v_mfma_f32_16x16x16_bf16 %0, %2, %3, %1"
                 : "=&v"(d) : "v"(z), "v"(a), "v"(b));
    return d;
}
__device__ __forceinline__ void mfma16_acc(v4f& acc, s16x4 a, s16x4 b) {
    asm volatile("v_mfma_f32_16x16x16_bf16 %0, %1, %2, %0"
                 : "+v"(acc) : "v"(a), "v"(b));
}

// ---------------------------------------------------------------------------
// Kernel 0: exp(trans) fragments + chunk-count prefix sums (32-step chunks).
// A-frag (I,K): lane holds E[I*16+(l&15)][K*16+(l>>4)*4+i], bf16.
// B-frag (K,J): lane holds E[K*16+(l>>4)*4+i][J*16+(l&15)], f32.
// ---------------------------------------------------------------------------
__global__ void __launch_bounds__(64)
crf_setup(const float* __restrict__ trans, const int* __restrict__ seqlen,
          void* ws) {
    __shared__ float el[NT * NT];
    const int lane = threadIdx.x, ln = lane & 15, g = lane >> 4;
    #pragma unroll
    for (int m = 0; m < 36; ++m) {
        int idx = lane + 64 * m;
        el[idx] = __expf(trans[idx]);
    }
    u32x2* AF = (u32x2*)((char*)ws + TAF16);
    v4f*   BF = (v4f*)((char*)ws + TBF);
    #pragma unroll
    for (int I = 0; I < 3; ++I)
        #pragma unroll
        for (int K = 0; K < 3; ++K) {
            const v4f ev = *(const v4f*)&el[(I * 16 + ln) * NT + K * 16 + g * 4];
            AF[(I * 3 + K) * 64 + lane] = (u32x2){pkbf(ev.x, ev.y), pkbf(ev.z, ev.w)};
        }
    #pragma unroll
    for (int K = 0; K < 3; ++K)
        #pragma unroll
        for (int J = 0; J < 3; ++J) {
            v4f v;
            #pragma unroll
            for (int i = 0; i < 4; ++i)
                v[i] = el[(K * 16 + g * 4 + i) * NT + J * 16 + ln];
            BF[(K * 3 + J) * 64 + lane] = v;
        }
    if (lane == 0) {
        int* cum = (int*)((char*)ws + TCUM);
        int acc = 0;
        for (int b = 0; b < BATCH; ++b) {
            cum[b] = acc;
            int L = seqlen[b];
            if (L < 1) L = 1;
            if (L > SEQ) L = SEQ;
            acc += (L + 31) >> 5;
        }
        cum[BATCH] = acc;
    }
}

// ---------------------------------------------------------------------------
// Kernel 1 (compacted): wave widx handles the widx-th ACTIVE 32-step chunk
// (binary search over cum[]).  Per chunk: K16 MFMA chain (r13-proven):
// acc = E*M (27 MFMA, 3 levels x 9, asm-pinned), gn = raw P00,
// M' = acc .* (em * 1/gn_prev), Lc += log2(gn) lagged.  Emissions pre-exp'd
// into wave-private LDS (24.6KB/WG).
// SINGLE-VARIABLE EXPERIMENT vs r13 (total 130.5us, occ 35%): bounds
// (256,4) -> (256,6).  VGPR cap ~85 (52-reg body fits, no r14 spill);
// LDS 24.6KB x 6 = 147.5 <= 160KB.  r13/r15 showed residency pinned ~3
// waves/SIMD (issue util only ~22%); r14 showed min-waves=8 -> occ 81%.
// ---------------------------------------------------------------------------
__global__ void __launch_bounds__(256, 6)
crf_phase1c(const float* __restrict__ feat, const int* __restrict__ seqlen,
            void* __restrict__ ws) {
    const int wid = threadIdx.x >> 6;
    const int widx = blockIdx.x * 4 + wid;
    const int* cum = (const int*)((const char*)ws + TCUM);
    if (widx >= cum[BATCH]) return;

    int lo = 0, hi = BATCH;          // invariant: cum[lo] <= widx < cum[hi]
    #pragma unroll
    for (int it = 0; it < 8; ++it) {
        int mid = (lo + hi) >> 1;
        if (cum[mid] <= widx) lo = mid; else hi = mid;
    }
    const int b = lo;
    const int c = widx - cum[b];
    const int t0 = c * 32;
    const int L = seqlen[b];
    int n = L - t0;
    if (n > 32) n = 32;

    const int lane = threadIdx.x & 63, ln = lane & 15, g = lane >> 4;

    __shared__ v4f flv[4][32 * 12];
    v4f* fl = flv[wid];

    s16x4 aw[3][3];
    {
        const u32x2* AF = (const u32x2*)((const char*)ws + TAF16);
        #pragma unroll
        for (int I = 0; I < 3; ++I)
            #pragma unroll
            for (int K = 0; K < 3; ++K)
                aw[I][K] = __builtin_bit_cast(s16x4, AF[(I * 3 + K) * 64 + lane]);
    }

    // stage rows t0..t0+31 (t0 <= 2016, in-bounds), exp() applied once
    {
        const v4f* fg = (const v4f*)(feat + ((size_t)b * SEQ + t0) * NT);
        #pragma unroll
        for (int m = 0; m < 6; ++m) {
            v4f v = fg[m * 64 + lane];
            v4f e;
            #pragma unroll
            for (int i = 0; i < 4; ++i) e[i] = __expf(v[i]);
            fl[m * 64 + lane] = e;
        }
    }

    // init M = D_{t0} E
    s16x4 mw[3][3];
    {
        const v4f* BF = (const v4f*)((const char*)ws + TBF);
        v4f em[3];
        #pragma unroll
        for (int K = 0; K < 3; ++K) em[K] = fl[K * 4 + g];
        #pragma unroll
        for (int K = 0; K < 3; ++K)
            #pragma unroll
            for (int J = 0; J < 3; ++J) {
                v4f sc = BF[(K * 3 + J) * 64 + lane] * em[K];
                mw[K][J] = __builtin_bit_cast(s16x4,
                    (u32x2){pkbf(sc.x, sc.y), pkbf(sc.z, sc.w)});
            }
    }

    float Lc = 0.f, lg = 0.f, s = 1.f;
    const v4f kz = {0.f, 0.f, 0.f, 0.f};

    for (int t = 1; t < n; ++t) {
        v4f em[3];
        #pragma unroll
        for (int K = 0; K < 3; ++K) em[K] = fl[t * 12 + K * 4 + g];

        v4f acc[3][3];
        #pragma unroll
        for (int I = 0; I < 3; ++I)
            #pragma unroll
            for (int J = 0; J < 3; ++J)
                acc[I][J] = mfma16_z(aw[I][0], mw[0][J], kz);
        #pragma unroll
        for (int I = 0; I < 3; ++I)
            #pragma unroll
            for (int J = 0; J < 3; ++J)
                mfma16_acc(acc[I][J], aw[I][1], mw[1][J]);
        #pragma unroll
        for (int I = 0; I < 3; ++I)
            #pragma unroll
            for (int J = 0; J < 3; ++J)
                mfma16_acc(acc[I][J], aw[I][2], mw[2][J]);
        asm volatile("s_nop 7\n\ts_nop 7");
        __builtin_amdgcn_sched_barrier(0);

        const float gn = rfl(acc[0][0].x);
        Lc += lg;
        #pragma unroll
        for (int K = 0; K < 3; ++K) {
            v4f sp = em[K] * s;
            #pragma unroll
            for (int J = 0; J < 3; ++J) {
                v4f sc = acc[K][J] * sp;
                mw[K][J] = __builtin_bit_cast(s16x4,
                    (u32x2){pkbf(sc.x, sc.y), pkbf(sc.z, sc.w)});
            }
        }
        lg = __log2f(gn);
        s  = __builtin_amdgcn_rcpf(gn);
    }

    // store M^T bf16 (element M[kk][nn] -> byte 2*(nn*48+kk)) + scale
    char* wb = (char*)ws + TW + ((size_t)(b * 64 + c)) * 4608;
    #pragma unroll
    for (int K = 0; K < 3; ++K)
        #pragma unroll
        for (int J = 0; J < 3; ++J) {
            u32x2 w = __builtin_bit_cast(u32x2, mw[K][J]);
            *(u32*)(wb + 2 * ((J * 16 + ln) * NT + K * 16 + g * 4))     = w.x;
            *(u32*)(wb + 2 * ((J * 16 + ln) * NT + K * 16 + g * 4 + 2)) = w.y;
        }
    if (lane == 0)
        ((float*)((char*)ws + TSC))[b * 64 + c] = Lc;
}

// ---------------------------------------------------------------------------
// Kernel 2: per sample, u^T <- u^T * M_c for c = nb-1..0; lane j owns u[j];
// M^T row j contiguous bf16; next chunk's row double-buffered.
// ---------------------------------------------------------------------------
__global__ void __launch_bounds__(64)
crf_phase2(const float* __restrict__ trans, const int* __restrict__ seqlen,
           const void* __restrict__ ws, float* __restrict__ out) {
    const int b = blockIdx.x;
    const int lane = threadIdx.x;
    const int j = (lane < NT) ? lane : (lane - 16);
    __shared__ v4f hs4[12];
    float* hs = (float*)hs4;

    const int L = seqlen[b];
    const int nb = (L + 31) / 32;
    const float* sc = (const float*)((const char*)ws + TSC) + b * 64;
    const char* wbase = (const char*)ws + TW + (size_t)b * 64 * 4608;

    float q = __expf(trans[END_TAG * NT + j]);   // u0 (exp(MIN)=0 -> col END)
    float D = 0.f;

    u32x4 buf[6];
    {
        const u32x4* wr = (const u32x4*)(wbase + (size_t)(nb - 1) * 4608 + j * 96);
        #pragma unroll
        for (int m = 0; m < 6; ++m) buf[m] = wr[m];
    }

    for (int c = nb - 1; c >= 0; --c) {
        u32x4 cur[6];
        #pragma unroll
        for (int m = 0; m < 6; ++m) cur[m] = buf[m];
        if (c > 0) {
            const u32x4* wr = (const u32x4*)(wbase + (size_t)(c - 1) * 4608 + j * 96);
            #pragma unroll
            for (int m = 0; m < 6; ++m) buf[m] = wr[m];
        }

        if (lane < NT) hs[lane] = q;
        v4f hq[12];
        #pragma unroll
        for (int k = 0; k < 12; ++k) hq[k] = hs4[k];
        const float h0 = hq[0][0];

        v2f a = {0.f, 0.f};
        #pragma unroll
        for (int m = 0; m < 6; ++m) {
            #pragma unroll
            for (int p = 0; p < 4; ++p) {
                const int i = 2 * (4 * m + p);
                u32 wv = cur[m][p];
                v2f wp;
                wp.x = bflo(wv);
                wp.y = bfhi(wv);
                v2f up = { hq[i >> 2][i & 3], hq[i >> 2][(i & 3) + 1] };
                a += wp * up;
            }
        }
        const float dot = a.x + a.y;
        q = dot * __builtin_amdgcn_rcpf(h0);
        D += __log2f(h0) + sc[c];
    }
    if (lane < NT) hs[lane] = q;
    if (lane == 0)
        out[b] = LN2f * (D + __log2f(hs[START_TAG]));
}

// ---------------------------------------------------------------------------
// Fallback: proven round-2 scalar kernel (ws too small)
// ---------------------------------------------------------------------------
__global__ void __launch_bounds__(64)
crf_scalar(const float* __restrict__ features, const float* __restrict__ transitions,
           const int* __restrict__ seq_len, float* __restrict__ out) {
    const int b = blockIdx.x;
    const int lane = threadIdx.x;
    const int j = (lane < NT) ? lane : (lane - 16);
    __shared__ v4f hs4[NT / 4];
    float* hs = (float*)hs4;

    v2f E2[NT / 2];
    {
        const v4f* trow = (const v4f*)(transitions + j * NT);
        #pragma unroll
        for (int k = 0; k < NT / 4; ++k) {
            v4f tv = trow[k];
            E2[2 * k].x = __expf(tv.x); E2[2 * k].y = __expf(tv.y);
            E2[2 * k + 1].x = __expf(tv.z); E2[2 * k + 1].y = __expf(tv.w);
        }
    }
    const float Eend = __expf(transitions[END_TAG * NT + j]);
    const int L = seq_len[b];
    const float* fbase = features + ((size_t)b * SEQ) * NT + j;

    float q = E2[START_TAG / 2].x * __expf(fbase[0]);
    float Clog2 = 0.0f;
    if (lane < NT) hs[lane] = q;

    float fb[8];
    #pragma unroll
    for (int u = 0; u < 8; ++u) {
        int tp = 1 + u;
        fb[u] = fbase[(size_t)(tp < SEQ ? tp : 0) * NT];
    }

    auto STEP = [&](float femit) {
        v4f hq[NT / 4];
        #pragma unroll
        for (int k = 0; k < NT / 4; ++k) hq[k] = hs4[k];
        float h0 = hq[0].x;
        float r = __builtin_amdgcn_rcpf(h0);
        float e = __expf(femit);
        float re = r * e;
        v2f a0 = {0.f, 0.f}, a1 = {0.f, 0.f};
        #pragma unroll
        for (int k = 0; k < NT / 4; ++k) {
            v2f lo = { hq[k].x, hq[k].y };
            v2f hi = { hq[k].z, hq[k].w };
            a0 += E2[2 * k] * lo;
            a1 += E2[2 * k + 1] * hi;
        }
        float d = (a0.x + a1.x) + (a0.y + a1.y);
        q = d * re;
        Clog2 += __log2f(h0);
        if (lane < NT) hs[lane] = q;
    };

    int t = 1;
    while (t + 8 <= L) {
        #pragma unroll
        for (int u = 0; u < 8; ++u) {
            STEP(fb[u]);
            int tp = t + u + 8;
            fb[u] = fbase[(size_t)(tp < SEQ ? tp : 0) * NT];
        }
        t += 8;
    }
    #pragma unroll
    for (int u = 0; u < 8; ++u)
        if (t + u < L) STEP(fb[u]);

    float term = (lane < NT) ? q * Eend : 0.0f;
    #pragma unroll
    for (int m = 32; m >= 1; m >>= 1) term += __shfl_xor(term, m, 64);
    if (lane == 0) out[b] = LN2f * (Clog2 + __log2f(term));
}

extern "C" void kernel_launch(void* const* d_in, const int* in_sizes, int n_in,
                              void* d_out, int out_size, void* d_ws, size_t ws_size,
                              hipStream_t stream) {
    const float* features    = (const float*)d_in[0];
    const float* transitions = (const float*)d_in[1];
    const int*   seqlen      = (const int*)d_in[2];
    float* out = (float*)d_out;

    const size_t need = (size_t)TW + (size_t)BATCH * 64 * 4608;   // ~75.7 MB
    if (ws_size >= need) {
        crf_setup<<<1, 64, 0, stream>>>(transitions, seqlen, d_ws);
        crf_phase1c<<<4096, 256, 0, stream>>>(features, seqlen, d_ws);
        crf_phase2<<<BATCH, 64, 0, stream>>>(transitions, seqlen, d_ws, out);
    } else {
        crf_scalar<<<BATCH, 64, 0, stream>>>(features, transitions, seqlen, out);
    }
}

// Round 17
// 140.711 us; speedup vs baseline: 1.7706x; 1.7706x over previous
//
#include <hip/hip_runtime.h>

#define BATCH 256
#define SEQ 2048
#define NT 48
#define START_TAG 46
#define END_TAG 47
#define LN2f  0.6931471805599453f

// ws layout
#define TAF16 0        // K16 A-frags exp(trans) bf16: [9][64] x 8B  = 4608
#define TBF   4608     // B-frag exp(trans) f32: [9][64] x 16B       = 9216
#define TCUM  13824    // prefix sums: int cum[257] (cum[0]=0)       = 1028
#define TSC   16384    // per-chunk log2 scales: [B][64] f32         = 64KiB
#define TW    163840   // chunk matrices M^T bf16: [B][64][48][48]

typedef float v2f __attribute__((ext_vector_type(2)));
typedef float v4f __attribute__((ext_vector_type(4)));
typedef short s16x4 __attribute__((ext_vector_type(4)));
typedef unsigned int u32;
typedef u32 u32x2 __attribute__((ext_vector_type(2)));
typedef u32 u32x4 __attribute__((ext_vector_type(4)));

__device__ __forceinline__ u32 pkbf(float a, float b) {
    u32 r;
    asm("v_cvt_pk_bf16_f32 %0, %1, %2" : "=v"(r) : "v"(a), "v"(b));
    return r;
}
__device__ __forceinline__ float bflo(u32 w) { return __builtin_bit_cast(float, w << 16); }
__device__ __forceinline__ float bfhi(u32 w) { return __builtin_bit_cast(float, w & 0xffff0000u); }

__device__ __forceinline__ float rfl(float x) {
    return __builtin_bit_cast(float,
        __builtin_amdgcn_readfirstlane(__builtin_bit_cast(int, x)));
}

__device__ __forceinline__ v4f mfma16_z(s16x4 a, s16x4 b, v4f z) {
    v4f d;
    asm volatile("v_mfma_f32_16x16x16_bf16 %0, %2, %3, %1"
                 : "=&v"(d) : "v"(z), "v"(a), "v"(b));
    return d;
}
__device__ __forceinline__ void mfma16_acc(v4f& acc, s16x4 a, s16x4 b) {
    asm volatile("v_mfma_f32_16x16x16_bf16 %0, %1, %2, %0"
                 : "+v"(acc) : "v"(a), "v"(b));
}

// ---------------------------------------------------------------------------
// Kernel 0: exp(trans) fragments + chunk-count prefix sums (32-step chunks).
// A-frag (I,K): lane holds E[I*16+(l&15)][K*16+(l>>4)*4+i], bf16.
// B-frag (K,J): lane holds E[K*16+(l>>4)*4+i][J*16+(l&15)], f32.
// ---------------------------------------------------------------------------
__global__ void __launch_bounds__(64)
crf_setup(const float* __restrict__ trans, const int* __restrict__ seqlen,
          void* ws) {
    __shared__ float el[NT * NT];
    const int lane = threadIdx.x, ln = lane & 15, g = lane >> 4;
    #pragma unroll
    for (int m = 0; m < 36; ++m) {
        int idx = lane + 64 * m;
        el[idx] = __expf(trans[idx]);
    }
    u32x2* AF = (u32x2*)((char*)ws + TAF16);
    v4f*   BF = (v4f*)((char*)ws + TBF);
    #pragma unroll
    for (int I = 0; I < 3; ++I)
        #pragma unroll
        for (int K = 0; K < 3; ++K) {
            const v4f ev = *(const v4f*)&el[(I * 16 + ln) * NT + K * 16 + g * 4];
            AF[(I * 3 + K) * 64 + lane] = (u32x2){pkbf(ev.x, ev.y), pkbf(ev.z, ev.w)};
        }
    #pragma unroll
    for (int K = 0; K < 3; ++K)
        #pragma unroll
        for (int J = 0; J < 3; ++J) {
            v4f v;
            #pragma unroll
            for (int i = 0; i < 4; ++i)
                v[i] = el[(K * 16 + g * 4 + i) * NT + J * 16 + ln];
            BF[(K * 3 + J) * 64 + lane] = v;
        }
    if (lane == 0) {
        int* cum = (int*)((char*)ws + TCUM);
        int acc = 0;
        for (int b = 0; b < BATCH; ++b) {
            cum[b] = acc;
            int L = seqlen[b];
            if (L < 1) L = 1;
            if (L > SEQ) L = SEQ;
            acc += (L + 31) >> 5;
        }
        cum[BATCH] = acc;
    }
}

// ---------------------------------------------------------------------------
// Kernel 1 (compacted DUAL-chain): wave pidx owns ACTIVE chunks 2p and 2p+1
// (independent binary searches; chains may belong to different samples).
// Per step: the two 27-MFMA level blocks are interleaved A,B per level so
// ~2x issue work packs into each latency window (r10-proven ILP), on top of
// r13's compaction (no dead resident waves).  K16 math unchanged (absmax 0
// since r12): acc = E*M, gn = raw P00, M' = acc .* (em * 1/gn_prev),
// Lc += log2(gn) lagged.  Emissions pre-exp'd into wave-private LDS
// (2 x 6.1KB per wave; 49KB/WG -> 3 WG/CU).
// __launch_bounds__(256,3): VGPR cap ~170 -> dual body (~88-120 VGPR,
// r10 measured 88) compiles spill-free.  r14/r16 lesson: caps < ~128 spill
// this body catastrophically; occupancy must come from ILP, not the bound.
// ---------------------------------------------------------------------------
__global__ void __launch_bounds__(256, 3)
crf_phase1d(const float* __restrict__ feat, const int* __restrict__ seqlen,
            void* __restrict__ ws) {
    const int wid = threadIdx.x >> 6;
    const int pidx = blockIdx.x * 4 + wid;
    const int* cum = (const int*)((const char*)ws + TCUM);
    const int total = cum[BATCH];
    const int iA = 2 * pidx, iB = 2 * pidx + 1;
    if (iA >= total) return;
    const bool hasB = (iB < total);

    int bA, cA, bB = 0, cB = 0;
    {
        int lo = 0, hi = BATCH;
        #pragma unroll
        for (int it = 0; it < 8; ++it) {
            int mid = (lo + hi) >> 1;
            if (cum[mid] <= iA) lo = mid; else hi = mid;
        }
        bA = lo; cA = iA - cum[lo];
    }
    if (hasB) {
        int lo = 0, hi = BATCH;
        #pragma unroll
        for (int it = 0; it < 8; ++it) {
            int mid = (lo + hi) >> 1;
            if (cum[mid] <= iB) lo = mid; else hi = mid;
        }
        bB = lo; cB = iB - cum[lo];
    }

    int nA = seqlen[bA] - cA * 32;
    if (nA > 32) nA = 32;
    int nB = 0;
    if (hasB) {
        nB = seqlen[bB] - cB * 32;
        if (nB > 32) nB = 32;
    }

    const int lane = threadIdx.x & 63, ln = lane & 15, g = lane >> 4;

    __shared__ v4f flv[4][2][32 * 12];   // per-wave: 2 chains x 32 rows x 12
    v4f* flA = flv[wid][0];
    v4f* flB = flv[wid][1];

    s16x4 aw[3][3];
    {
        const u32x2* AF = (const u32x2*)((const char*)ws + TAF16);
        #pragma unroll
        for (int I = 0; I < 3; ++I)
            #pragma unroll
            for (int K = 0; K < 3; ++K)
                aw[I][K] = __builtin_bit_cast(s16x4, AF[(I * 3 + K) * 64 + lane]);
    }

    // stage both chains' emissions (rows always in-bounds), exp() once
    {
        const v4f* fg = (const v4f*)(feat + ((size_t)bA * SEQ + cA * 32) * NT);
        #pragma unroll
        for (int m = 0; m < 6; ++m) {
            v4f v = fg[m * 64 + lane];
            v4f e;
            #pragma unroll
            for (int i = 0; i < 4; ++i) e[i] = __expf(v[i]);
            flA[m * 64 + lane] = e;
        }
    }
    if (hasB) {
        const v4f* fg = (const v4f*)(feat + ((size_t)bB * SEQ + cB * 32) * NT);
        #pragma unroll
        for (int m = 0; m < 6; ++m) {
            v4f v = fg[m * 64 + lane];
            v4f e;
            #pragma unroll
            for (int i = 0; i < 4; ++i) e[i] = __expf(v[i]);
            flB[m * 64 + lane] = e;
        }
    }

    const v4f* BF = (const v4f*)((const char*)ws + TBF);
    const v4f kz = {0.f, 0.f, 0.f, 0.f};

    // init M = D_{t0} E per chain
    s16x4 mwA[3][3], mwB[3][3];
    {
        v4f em[3];
        #pragma unroll
        for (int K = 0; K < 3; ++K) em[K] = flA[K * 4 + g];
        #pragma unroll
        for (int K = 0; K < 3; ++K)
            #pragma unroll
            for (int J = 0; J < 3; ++J) {
                v4f sc = BF[(K * 3 + J) * 64 + lane] * em[K];
                mwA[K][J] = __builtin_bit_cast(s16x4,
                    (u32x2){pkbf(sc.x, sc.y), pkbf(sc.z, sc.w)});
            }
    }
    if (hasB) {
        v4f em[3];
        #pragma unroll
        for (int K = 0; K < 3; ++K) em[K] = flB[K * 4 + g];
        #pragma unroll
        for (int K = 0; K < 3; ++K)
            #pragma unroll
            for (int J = 0; J < 3; ++J) {
                v4f sc = BF[(K * 3 + J) * 64 + lane] * em[K];
                mwB[K][J] = __builtin_bit_cast(s16x4,
                    (u32x2){pkbf(sc.x, sc.y), pkbf(sc.z, sc.w)});
            }
    }

    float LcA = 0.f, lgA = 0.f, sA = 1.f;
    float LcB = 0.f, lgB = 0.f, sB = 1.f;

    // single-chain step (shared by tails)
    auto STEP1 = [&](s16x4 (&mw)[3][3], const v4f* fl, int t,
                     float& Lc, float& lg, float& s) {
        v4f em[3];
        #pragma unroll
        for (int K = 0; K < 3; ++K) em[K] = fl[t * 12 + K * 4 + g];
        v4f acc[3][3];
        #pragma unroll
        for (int I = 0; I < 3; ++I)
            #pragma unroll
            for (int J = 0; J < 3; ++J)
                acc[I][J] = mfma16_z(aw[I][0], mw[0][J], kz);
        #pragma unroll
        for (int I = 0; I < 3; ++I)
            #pragma unroll
            for (int J = 0; J < 3; ++J)
                mfma16_acc(acc[I][J], aw[I][1], mw[1][J]);
        #pragma unroll
        for (int I = 0; I < 3; ++I)
            #pragma unroll
            for (int J = 0; J < 3; ++J)
                mfma16_acc(acc[I][J], aw[I][2], mw[2][J]);
        asm volatile("s_nop 7\n\ts_nop 7");
        __builtin_amdgcn_sched_barrier(0);
        const float gn = rfl(acc[0][0].x);
        Lc += lg;
        #pragma unroll
        for (int K = 0; K < 3; ++K) {
            v4f sp = em[K] * s;
            #pragma unroll
            for (int J = 0; J < 3; ++J) {
                v4f sc = acc[K][J] * sp;
                mw[K][J] = __builtin_bit_cast(s16x4,
                    (u32x2){pkbf(sc.x, sc.y), pkbf(sc.z, sc.w)});
            }
        }
        lg = __log2f(gn);
        s  = __builtin_amdgcn_rcpf(gn);
    };

    const int td = hasB ? (nA < nB ? nA : nB) : 0;
    int t = 1;
    for (; t < td; ++t) {           // dual loop: levels interleaved A,B
        v4f emA[3], emB[3];
        #pragma unroll
        for (int K = 0; K < 3; ++K) emA[K] = flA[t * 12 + K * 4 + g];
        #pragma unroll
        for (int K = 0; K < 3; ++K) emB[K] = flB[t * 12 + K * 4 + g];

        v4f accA[3][3], accB[3][3];
        #pragma unroll
        for (int I = 0; I < 3; ++I)
            #pragma unroll
            for (int J = 0; J < 3; ++J)
                accA[I][J] = mfma16_z(aw[I][0], mwA[0][J], kz);
        #pragma unroll
        for (int I = 0; I < 3; ++I)
            #pragma unroll
            for (int J = 0; J < 3; ++J)
                accB[I][J] = mfma16_z(aw[I][0], mwB[0][J], kz);
        #pragma unroll
        for (int I = 0; I < 3; ++I)
            #pragma unroll
            for (int J = 0; J < 3; ++J)
                mfma16_acc(accA[I][J], aw[I][1], mwA[1][J]);
        #pragma unroll
        for (int I = 0; I < 3; ++I)
            #pragma unroll
            for (int J = 0; J < 3; ++J)
                mfma16_acc(accB[I][J], aw[I][1], mwB[1][J]);
        #pragma unroll
        for (int I = 0; I < 3; ++I)
            #pragma unroll
            for (int J = 0; J < 3; ++J)
                mfma16_acc(accA[I][J], aw[I][2], mwA[2][J]);
        #pragma unroll
        for (int I = 0; I < 3; ++I)
            #pragma unroll
            for (int J = 0; J < 3; ++J)
                mfma16_acc(accB[I][J], aw[I][2], mwB[2][J]);
        asm volatile("s_nop 7\n\ts_nop 7");
        __builtin_amdgcn_sched_barrier(0);

        const float gnA = rfl(accA[0][0].x);
        const float gnB = rfl(accB[0][0].x);
        LcA += lgA;
        LcB += lgB;
        #pragma unroll
        for (int K = 0; K < 3; ++K) {
            v4f spA = emA[K] * sA;
            v4f spB = emB[K] * sB;
            #pragma unroll
            for (int J = 0; J < 3; ++J) {
                v4f scA = accA[K][J] * spA;
                v4f scB = accB[K][J] * spB;
                mwA[K][J] = __builtin_bit_cast(s16x4,
                    (u32x2){pkbf(scA.x, scA.y), pkbf(scA.z, scA.w)});
                mwB[K][J] = __builtin_bit_cast(s16x4,
                    (u32x2){pkbf(scB.x, scB.y), pkbf(scB.z, scB.w)});
            }
        }
        lgA = __log2f(gnA);
        sA  = __builtin_amdgcn_rcpf(gnA);
        lgB = __log2f(gnB);
        sB  = __builtin_amdgcn_rcpf(gnB);
    }
    for (int ta = t; ta < nA; ++ta) STEP1(mwA, flA, ta, LcA, lgA, sA);
    for (int tb = t; tb < nB; ++tb) STEP1(mwB, flB, tb, LcB, lgB, sB);

    // store M^T bf16 (element M[kk][nn] -> byte 2*(nn*48+kk)) + scales
    {
        char* wb = (char*)ws + TW + ((size_t)(bA * 64 + cA)) * 4608;
        #pragma unroll
        for (int K = 0; K < 3; ++K)
            #pragma unroll
            for (int J = 0; J < 3; ++J) {
                u32x2 w = __builtin_bit_cast(u32x2, mwA[K][J]);
                *(u32*)(wb + 2 * ((J * 16 + ln) * NT + K * 16 + g * 4))     = w.x;
                *(u32*)(wb + 2 * ((J * 16 + ln) * NT + K * 16 + g * 4 + 2)) = w.y;
            }
        if (lane == 0)
            ((float*)((char*)ws + TSC))[bA * 64 + cA] = LcA;
    }
    if (hasB) {
        char* wb = (char*)ws + TW + ((size_t)(bB * 64 + cB)) * 4608;
        #pragma unroll
        for (int K = 0; K < 3; ++K)
            #pragma unroll
            for (int J = 0; J < 3; ++J) {
                u32x2 w = __builtin_bit_cast(u32x2, mwB[K][J]);
                *(u32*)(wb + 2 * ((J * 16 + ln) * NT + K * 16 + g * 4))     = w.x;
                *(u32*)(wb + 2 * ((J * 16 + ln) * NT + K * 16 + g * 4 + 2)) = w.y;
            }
        if (lane == 0)
            ((float*)((char*)ws + TSC))[bB * 64 + cB] = LcB;
    }
}

// ---------------------------------------------------------------------------
// Kernel 2: per sample, u^T <- u^T * M_c for c = nb-1..0; lane j owns u[j];
// M^T row j contiguous bf16; next chunk's row double-buffered.
// ---------------------------------------------------------------------------
__global__ void __launch_bounds__(64)
crf_phase2(const float* __restrict__ trans, const int* __restrict__ seqlen,
           const void* __restrict__ ws, float* __restrict__ out) {
    const int b = blockIdx.x;
    const int lane = threadIdx.x;
    const int j = (lane < NT) ? lane : (lane - 16);
    __shared__ v4f hs4[12];
    float* hs = (float*)hs4;

    const int L = seqlen[b];
    const int nb = (L + 31) / 32;
    const float* sc = (const float*)((const char*)ws + TSC) + b * 64;
    const char* wbase = (const char*)ws + TW + (size_t)b * 64 * 4608;

    float q = __expf(trans[END_TAG * NT + j]);   // u0 (exp(MIN)=0 -> col END)
    float D = 0.f;

    u32x4 buf[6];
    {
        const u32x4* wr = (const u32x4*)(wbase + (size_t)(nb - 1) * 4608 + j * 96);
        #pragma unroll
        for (int m = 0; m < 6; ++m) buf[m] = wr[m];
    }

    for (int c = nb - 1; c >= 0; --c) {
        u32x4 cur[6];
        #pragma unroll
        for (int m = 0; m < 6; ++m) cur[m] = buf[m];
        if (c > 0) {
            const u32x4* wr = (const u32x4*)(wbase + (size_t)(c - 1) * 4608 + j * 96);
            #pragma unroll
            for (int m = 0; m < 6; ++m) buf[m] = wr[m];
        }

        if (lane < NT) hs[lane] = q;
        v4f hq[12];
        #pragma unroll
        for (int k = 0; k < 12; ++k) hq[k] = hs4[k];
        const float h0 = hq[0][0];

        v2f a = {0.f, 0.f};
        #pragma unroll
        for (int m = 0; m < 6; ++m) {
            #pragma unroll
            for (int p = 0; p < 4; ++p) {
                const int i = 2 * (4 * m + p);
                u32 wv = cur[m][p];
                v2f wp;
                wp.x = bflo(wv);
                wp.y = bfhi(wv);
                v2f up = { hq[i >> 2][i & 3], hq[i >> 2][(i & 3) + 1] };
                a += wp * up;
            }
        }
        const float dot = a.x + a.y;
        q = dot * __builtin_amdgcn_rcpf(h0);
        D += __log2f(h0) + sc[c];
    }
    if (lane < NT) hs[lane] = q;
    if (lane == 0)
        out[b] = LN2f * (D + __log2f(hs[START_TAG]));
}

// ---------------------------------------------------------------------------
// Fallback: proven round-2 scalar kernel (ws too small)
// ---------------------------------------------------------------------------
__global__ void __launch_bounds__(64)
crf_scalar(const float* __restrict__ features, const float* __restrict__ transitions,
           const int* __restrict__ seq_len, float* __restrict__ out) {
    const int b = blockIdx.x;
    const int lane = threadIdx.x;
    const int j = (lane < NT) ? lane : (lane - 16);
    __shared__ v4f hs4[NT / 4];
    float* hs = (float*)hs4;

    v2f E2[NT / 2];
    {
        const v4f* trow = (const v4f*)(transitions + j * NT);
        #pragma unroll
        for (int k = 0; k < NT / 4; ++k) {
            v4f tv = trow[k];
            E2[2 * k].x = __expf(tv.x); E2[2 * k].y = __expf(tv.y);
            E2[2 * k + 1].x = __expf(tv.z); E2[2 * k + 1].y = __expf(tv.w);
        }
    }
    const float Eend = __expf(transitions[END_TAG * NT + j]);
    const int L = seq_len[b];
    const float* fbase = features + ((size_t)b * SEQ) * NT + j;

    float q = E2[START_TAG / 2].x * __expf(fbase[0]);
    float Clog2 = 0.0f;
    if (lane < NT) hs[lane] = q;

    float fb[8];
    #pragma unroll
    for (int u = 0; u < 8; ++u) {
        int tp = 1 + u;
        fb[u] = fbase[(size_t)(tp < SEQ ? tp : 0) * NT];
    }

    auto STEP = [&](float femit) {
        v4f hq[NT / 4];
        #pragma unroll
        for (int k = 0; k < NT / 4; ++k) hq[k] = hs4[k];
        float h0 = hq[0].x;
        float r = __builtin_amdgcn_rcpf(h0);
        float e = __expf(femit);
        float re = r * e;
        v2f a0 = {0.f, 0.f}, a1 = {0.f, 0.f};
        #pragma unroll
        for (int k = 0; k < NT / 4; ++k) {
            v2f lo = { hq[k].x, hq[k].y };
            v2f hi = { hq[k].z, hq[k].w };
            a0 += E2[2 * k] * lo;
            a1 += E2[2 * k + 1] * hi;
        }
        float d = (a0.x + a1.x) + (a0.y + a1.y);
        q = d * re;
        Clog2 += __log2f(h0);
        if (lane < NT) hs[lane] = q;
    };

    int t = 1;
    while (t + 8 <= L) {
        #pragma unroll
        for (int u = 0; u < 8; ++u) {
            STEP(fb[u]);
            int tp = t + u + 8;
            fb[u] = fbase[(size_t)(tp < SEQ ? tp : 0) * NT];
        }
        t += 8;
    }
    #pragma unroll
    for (int u = 0; u < 8; ++u)
        if (t + u < L) STEP(fb[u]);

    float term = (lane < NT) ? q * Eend : 0.0f;
    #pragma unroll
    for (int m = 32; m >= 1; m >>= 1) term += __shfl_xor(term, m, 64);
    if (lane == 0) out[b] = LN2f * (Clog2 + __log2f(term));
}

extern "C" void kernel_launch(void* const* d_in, const int* in_sizes, int n_in,
                              void* d_out, int out_size, void* d_ws, size_t ws_size,
                              hipStream_t stream) {
    const float* features    = (const float*)d_in[0];
    const float* transitions = (const float*)d_in[1];
    const int*   seqlen      = (const int*)d_in[2];
    float* out = (float*)d_out;

    const size_t need = (size_t)TW + (size_t)BATCH * 64 * 4608;   // ~75.7 MB
    if (ws_size >= need) {
        crf_setup<<<1, 64, 0, stream>>>(transitions, seqlen, d_ws);
        // worst case 16384 chunks -> 8192 pairs -> 2048 WGs of 4 pair-waves
        crf_phase1d<<<2048, 256, 0, stream>>>(features, seqlen, d_ws);
        crf_phase2<<<BATCH, 64, 0, stream>>>(transitions, seqlen, d_ws, out);
    } else {
        crf_scalar<<<BATCH, 64, 0, stream>>>(features, transitions, seqlen, out);
    }
}

// Round 18
// 120.985 us; speedup vs baseline: 2.0593x; 1.1631x over previous
//
#include <hip/hip_runtime.h>

#define BATCH 256
#define SEQ 2048
#define NT 48
#define START_TAG 46
#define END_TAG 47
#define LN2f  0.6931471805599453f

// ws layout
#define TAF16 0        // K16 A-frags exp(trans) bf16: [9][64] x 8B  = 4608
#define TBF   4608     // B-frag exp(trans) f32: [9][64] x 16B       = 9216
#define TCUM  13824    // prefix sums: int cum[257] (cum[0]=0)       = 1028
#define TSC   16384    // per-chunk log2 scales: [B][64] f32         = 64KiB
#define TW    131072   // chunk matrices bf16: [B][64][48][48]
                       //   chunk c < h : M row-major   (left half, b <- M b)
                       //   chunk c >= h: M^T row-major (right half, u^T <- u^T M)

typedef float v2f __attribute__((ext_vector_type(2)));
typedef float v4f __attribute__((ext_vector_type(4)));
typedef short s16x4 __attribute__((ext_vector_type(4)));
typedef unsigned int u32;
typedef unsigned short u16;
typedef u32 u32x2 __attribute__((ext_vector_type(2)));
typedef u32 u32x4 __attribute__((ext_vector_type(4)));

__device__ __forceinline__ u32 pkbf(float a, float b) {
    u32 r;
    asm("v_cvt_pk_bf16_f32 %0, %1, %2" : "=v"(r) : "v"(a), "v"(b));
    return r;
}
__device__ __forceinline__ float bflo(u32 w) { return __builtin_bit_cast(float, w << 16); }
__device__ __forceinline__ float bfhi(u32 w) { return __builtin_bit_cast(float, w & 0xffff0000u); }

__device__ __forceinline__ float rfl(float x) {
    return __builtin_bit_cast(float,
        __builtin_amdgcn_readfirstlane(__builtin_bit_cast(int, x)));
}

__device__ __forceinline__ v4f mfma16_z(s16x4 a, s16x4 b, v4f z) {
    v4f d;
    asm volatile("v_mfma_f32_16x16x16_bf16 %0, %2, %3, %1"
                 : "=&v"(d) : "v"(z), "v"(a), "v"(b));
    return d;
}
__device__ __forceinline__ void mfma16_acc(v4f& acc, s16x4 a, s16x4 b) {
    asm volatile("v_mfma_f32_16x16x16_bf16 %0, %1, %2, %0"
                 : "+v"(acc) : "v"(a), "v"(b));
}

// ---------------------------------------------------------------------------
// Kernel 0: exp(trans) fragments + chunk-count prefix sums (32-step chunks).
// ---------------------------------------------------------------------------
__global__ void __launch_bounds__(64)
crf_setup(const float* __restrict__ trans, const int* __restrict__ seqlen,
          void* ws) {
    __shared__ float el[NT * NT];
    const int lane = threadIdx.x, ln = lane & 15, g = lane >> 4;
    #pragma unroll
    for (int m = 0; m < 36; ++m) {
        int idx = lane + 64 * m;
        el[idx] = __expf(trans[idx]);
    }
    u32x2* AF = (u32x2*)((char*)ws + TAF16);
    v4f*   BF = (v4f*)((char*)ws + TBF);
    #pragma unroll
    for (int I = 0; I < 3; ++I)
        #pragma unroll
        for (int K = 0; K < 3; ++K) {
            const v4f ev = *(const v4f*)&el[(I * 16 + ln) * NT + K * 16 + g * 4];
            AF[(I * 3 + K) * 64 + lane] = (u32x2){pkbf(ev.x, ev.y), pkbf(ev.z, ev.w)};
        }
    #pragma unroll
    for (int K = 0; K < 3; ++K)
        #pragma unroll
        for (int J = 0; J < 3; ++J) {
            v4f v;
            #pragma unroll
            for (int i = 0; i < 4; ++i)
                v[i] = el[(K * 16 + g * 4 + i) * NT + J * 16 + ln];
            BF[(K * 3 + J) * 64 + lane] = v;
        }
    if (lane == 0) {
        int* cum = (int*)((char*)ws + TCUM);
        int acc = 0;
        for (int b = 0; b < BATCH; ++b) {
            cum[b] = acc;
            int L = seqlen[b];
            if (L < 1) L = 1;
            if (L > SEQ) L = SEQ;
            acc += (L + 31) >> 5;
        }
        cum[BATCH] = acc;
    }
}

// ---------------------------------------------------------------------------
// Kernel 1 (r13-proven config): wave widx handles the widx-th ACTIVE 32-step
// chunk (binary search over cum[]).  K16 MFMA chain: acc = E*M (27 MFMA,
// 3 levels x 9, asm-pinned), gn = raw P00, M' = acc .* (em * 1/gn_prev),
// Lc += log2(gn) lagged.  Emissions pre-exp'd into wave-private LDS.
// __launch_bounds__(256,4): VGPR cap 128, 52-reg body spill-free (caps
// <=102 spill catastrophically — r14/r16).
// Store format is direction-aware for the split phase2: chunks c < h
// (h = nb/2) stored as M row-major, c >= h as M^T row-major.
// ---------------------------------------------------------------------------
__global__ void __launch_bounds__(256, 4)
crf_phase1c(const float* __restrict__ feat, const int* __restrict__ seqlen,
            void* __restrict__ ws) {
    const int wid = threadIdx.x >> 6;
    const int widx = blockIdx.x * 4 + wid;
    const int* cum = (const int*)((const char*)ws + TCUM);
    if (widx >= cum[BATCH]) return;

    int lo = 0, hi = BATCH;          // invariant: cum[lo] <= widx < cum[hi]
    #pragma unroll
    for (int it = 0; it < 8; ++it) {
        int mid = (lo + hi) >> 1;
        if (cum[mid] <= widx) lo = mid; else hi = mid;
    }
    const int b = lo;
    const int c = widx - cum[b];
    const int t0 = c * 32;
    int Lraw = seqlen[b];
    if (Lraw < 1) Lraw = 1;
    if (Lraw > SEQ) Lraw = SEQ;
    const int nbS = (Lraw + 31) >> 5;
    const int half = nbS >> 1;
    int n = Lraw - t0;
    if (n > 32) n = 32;

    const int lane = threadIdx.x & 63, ln = lane & 15, g = lane >> 4;

    __shared__ v4f flv[4][32 * 12];
    v4f* fl = flv[wid];

    s16x4 aw[3][3];
    {
        const u32x2* AF = (const u32x2*)((const char*)ws + TAF16);
        #pragma unroll
        for (int I = 0; I < 3; ++I)
            #pragma unroll
            for (int K = 0; K < 3; ++K)
                aw[I][K] = __builtin_bit_cast(s16x4, AF[(I * 3 + K) * 64 + lane]);
    }

    // stage rows t0..t0+31 (t0 <= 2016, in-bounds), exp() applied once
    {
        const v4f* fg = (const v4f*)(feat + ((size_t)b * SEQ + t0) * NT);
        #pragma unroll
        for (int m = 0; m < 6; ++m) {
            v4f v = fg[m * 64 + lane];
            v4f e;
            #pragma unroll
            for (int i = 0; i < 4; ++i) e[i] = __expf(v[i]);
            fl[m * 64 + lane] = e;
        }
    }

    // init M = D_{t0} E
    s16x4 mw[3][3];
    {
        const v4f* BF = (const v4f*)((const char*)ws + TBF);
        v4f em[3];
        #pragma unroll
        for (int K = 0; K < 3; ++K) em[K] = fl[K * 4 + g];
        #pragma unroll
        for (int K = 0; K < 3; ++K)
            #pragma unroll
            for (int J = 0; J < 3; ++J) {
                v4f sc = BF[(K * 3 + J) * 64 + lane] * em[K];
                mw[K][J] = __builtin_bit_cast(s16x4,
                    (u32x2){pkbf(sc.x, sc.y), pkbf(sc.z, sc.w)});
            }
    }

    float Lc = 0.f, lg = 0.f, s = 1.f;
    const v4f kz = {0.f, 0.f, 0.f, 0.f};

    for (int t = 1; t < n; ++t) {
        v4f em[3];
        #pragma unroll
        for (int K = 0; K < 3; ++K) em[K] = fl[t * 12 + K * 4 + g];

        v4f acc[3][3];
        #pragma unroll
        for (int I = 0; I < 3; ++I)
            #pragma unroll
            for (int J = 0; J < 3; ++J)
                acc[I][J] = mfma16_z(aw[I][0], mw[0][J], kz);
        #pragma unroll
        for (int I = 0; I < 3; ++I)
            #pragma unroll
            for (int J = 0; J < 3; ++J)
                mfma16_acc(acc[I][J], aw[I][1], mw[1][J]);
        #pragma unroll
        for (int I = 0; I < 3; ++I)
            #pragma unroll
            for (int J = 0; J < 3; ++J)
                mfma16_acc(acc[I][J], aw[I][2], mw[2][J]);
        asm volatile("s_nop 7\n\ts_nop 7");
        __builtin_amdgcn_sched_barrier(0);

        const float gn = rfl(acc[0][0].x);
        Lc += lg;
        #pragma unroll
        for (int K = 0; K < 3; ++K) {
            v4f sp = em[K] * s;
            #pragma unroll
            for (int J = 0; J < 3; ++J) {
                v4f sc = acc[K][J] * sp;
                mw[K][J] = __builtin_bit_cast(s16x4,
                    (u32x2){pkbf(sc.x, sc.y), pkbf(sc.z, sc.w)});
            }
        }
        lg = __log2f(gn);
        s  = __builtin_amdgcn_rcpf(gn);
    }

    // store: element M[row][col], row = K*16+g*4+i, col = J*16+ln.
    char* wb = (char*)ws + TW + ((size_t)(b * 64 + c)) * 4608;
    if (c >= half) {
        // M^T row-major (right half): byte 2*(col*48+row)
        #pragma unroll
        for (int K = 0; K < 3; ++K)
            #pragma unroll
            for (int J = 0; J < 3; ++J) {
                u32x2 w = __builtin_bit_cast(u32x2, mw[K][J]);
                *(u32*)(wb + 2 * ((J * 16 + ln) * NT + K * 16 + g * 4))     = w.x;
                *(u32*)(wb + 2 * ((J * 16 + ln) * NT + K * 16 + g * 4 + 2)) = w.y;
            }
    } else {
        // M row-major (left half): byte 2*(row*48+col)
        u16* mb = (u16*)wb;
        #pragma unroll
        for (int K = 0; K < 3; ++K)
            #pragma unroll
            for (int J = 0; J < 3; ++J) {
                u32x2 w = __builtin_bit_cast(u32x2, mw[K][J]);
                const int r0 = K * 16 + g * 4, col = J * 16 + ln;
                mb[(r0 + 0) * NT + col] = (u16)(w.x & 0xffff);
                mb[(r0 + 1) * NT + col] = (u16)(w.x >> 16);
                mb[(r0 + 2) * NT + col] = (u16)(w.y & 0xffff);
                mb[(r0 + 3) * NT + col] = (u16)(w.y >> 16);
            }
    }
    if (lane == 0)
        ((float*)((char*)ws + TSC))[b * 64 + c] = Lc;
}

// ---------------------------------------------------------------------------
// Kernel 2 (split): 128 threads per sample.  Associativity:
//   out = u0^T (M_{nb-1}..M_h) (M_{h-1}..M_0) e_START
// wave0: a^T <- a^T M_c, c = nb-1..h   (M^T rows, a0 = exp(trans[END][:]))
// wave1: b   <- M_c b,   c = 0..h-1    (M rows,   b0 = e_START)
// Both rescale by first element per hop (guarded for b0[0]=0) and track D.
// out = ln2*(Da + Db + log2(a . b)).
// ---------------------------------------------------------------------------
__global__ void __launch_bounds__(128)
crf_phase2s(const float* __restrict__ trans, const int* __restrict__ seqlen,
            const void* __restrict__ ws, float* __restrict__ out) {
    const int b = blockIdx.x;
    const int wave = threadIdx.x >> 6;
    const int lane = threadIdx.x & 63;
    const int j = (lane < NT) ? lane : (lane - 16);

    __shared__ v4f hsv[2][12];
    __shared__ float sres[2][NT];
    __shared__ float sD[2];
    float* hs = (float*)hsv[wave];

    int L = seqlen[b];
    if (L < 1) L = 1;
    if (L > SEQ) L = SEQ;
    const int nb = (L + 31) >> 5;
    const int half = nb >> 1;
    const float* sc = (const float*)((const char*)ws + TSC) + b * 64;
    const char* wbase = (const char*)ws + TW + (size_t)b * 64 * 4608;

    // per-wave chunk range and direction
    const int c0   = wave ? 0 : (nb - 1);      // first chunk
    const int cend = wave ? (half - 1) : half; // last chunk (inclusive)
    const int cstep = wave ? 1 : -1;
    const int nhops = wave ? half : (nb - half);

    float q = wave ? ((j == START_TAG) ? 1.f : 0.f)
                   : __expf(trans[END_TAG * NT + j]);
    float D = 0.f;

    if (nhops > 0) {
        u32x4 buf[6];
        {
            const u32x4* wr = (const u32x4*)(wbase + (size_t)c0 * 4608 + j * 96);
            #pragma unroll
            for (int m = 0; m < 6; ++m) buf[m] = wr[m];
        }
        for (int hh = 0; hh < nhops; ++hh) {
            const int c = c0 + hh * cstep;
            u32x4 cur[6];
            #pragma unroll
            for (int m = 0; m < 6; ++m) cur[m] = buf[m];
            if (hh + 1 < nhops) {
                const u32x4* wr =
                    (const u32x4*)(wbase + (size_t)(c + cstep) * 4608 + j * 96);
                #pragma unroll
                for (int m = 0; m < 6; ++m) buf[m] = wr[m];
            }

            if (lane < NT) hs[lane] = q;
            v4f hq[12];
            #pragma unroll
            for (int k = 0; k < 12; ++k) hq[k] = hsv[wave][k];
            const float h0 = hq[0][0];

            v2f a = {0.f, 0.f};
            #pragma unroll
            for (int m = 0; m < 6; ++m) {
                #pragma unroll
                for (int p = 0; p < 4; ++p) {
                    const int i = 2 * (4 * m + p);
                    u32 wv = cur[m][p];
                    v2f wp;
                    wp.x = bflo(wv);
                    wp.y = bfhi(wv);
                    v2f up = { hq[i >> 2][i & 3], hq[i >> 2][(i & 3) + 1] };
                    a += wp * up;
                }
            }
            const float dot = a.x + a.y;
            const bool ok = (h0 > 0.f);
            q = ok ? dot * __builtin_amdgcn_rcpf(h0) : dot;
            D += (ok ? __log2f(h0) : 0.f) + sc[c];
        }
    }

    if (lane < NT) sres[wave][j] = q;
    if (lane == 0) sD[wave] = D;
    __syncthreads();

    if (wave == 0) {
        float term = (lane < NT) ? sres[0][lane] * sres[1][lane] : 0.f;
        #pragma unroll
        for (int m = 32; m >= 1; m >>= 1) term += __shfl_xor(term, m, 64);
        if (lane == 0)
            out[b] = LN2f * (sD[0] + sD[1] + __log2f(term));
    }
}

// ---------------------------------------------------------------------------
// Fallback: proven round-2 scalar kernel (ws too small)
// ---------------------------------------------------------------------------
__global__ void __launch_bounds__(64)
crf_scalar(const float* __restrict__ features, const float* __restrict__ transitions,
           const int* __restrict__ seq_len, float* __restrict__ out) {
    const int b = blockIdx.x;
    const int lane = threadIdx.x;
    const int j = (lane < NT) ? lane : (lane - 16);
    __shared__ v4f hs4[NT / 4];
    float* hs = (float*)hs4;

    v2f E2[NT / 2];
    {
        const v4f* trow = (const v4f*)(transitions + j * NT);
        #pragma unroll
        for (int k = 0; k < NT / 4; ++k) {
            v4f tv = trow[k];
            E2[2 * k].x = __expf(tv.x); E2[2 * k].y = __expf(tv.y);
            E2[2 * k + 1].x = __expf(tv.z); E2[2 * k + 1].y = __expf(tv.w);
        }
    }
    const float Eend = __expf(transitions[END_TAG * NT + j]);
    const int L = seq_len[b];
    const float* fbase = features + ((size_t)b * SEQ) * NT + j;

    float q = E2[START_TAG / 2].x * __expf(fbase[0]);
    float Clog2 = 0.0f;
    if (lane < NT) hs[lane] = q;

    float fb[8];
    #pragma unroll
    for (int u = 0; u < 8; ++u) {
        int tp = 1 + u;
        fb[u] = fbase[(size_t)(tp < SEQ ? tp : 0) * NT];
    }

    auto STEP = [&](float femit) {
        v4f hq[NT / 4];
        #pragma unroll
        for (int k = 0; k < NT / 4; ++k) hq[k] = hs4[k];
        float h0 = hq[0].x;
        float r = __builtin_amdgcn_rcpf(h0);
        float e = __expf(femit);
        float re = r * e;
        v2f a0 = {0.f, 0.f}, a1 = {0.f, 0.f};
        #pragma unroll
        for (int k = 0; k < NT / 4; ++k) {
            v2f lo = { hq[k].x, hq[k].y };
            v2f hi = { hq[k].z, hq[k].w };
            a0 += E2[2 * k] * lo;
            a1 += E2[2 * k + 1] * hi;
        }
        float d = (a0.x + a1.x) + (a0.y + a1.y);
        q = d * re;
        Clog2 += __log2f(h0);
        if (lane < NT) hs[lane] = q;
    };

    int t = 1;
    while (t + 8 <= L) {
        #pragma unroll
        for (int u = 0; u < 8; ++u) {
            STEP(fb[u]);
            int tp = t + u + 8;
            fb[u] = fbase[(size_t)(tp < SEQ ? tp : 0) * NT];
        }
        t += 8;
    }
    #pragma unroll
    for (int u = 0; u < 8; ++u)
        if (t + u < L) STEP(fb[u]);

    float term = (lane < NT) ? q * Eend : 0.0f;
    #pragma unroll
    for (int m = 32; m >= 1; m >>= 1) term += __shfl_xor(term, m, 64);
    if (lane == 0) out[b] = LN2f * (Clog2 + __log2f(term));
}

extern "C" void kernel_launch(void* const* d_in, const int* in_sizes, int n_in,
                              void* d_out, int out_size, void* d_ws, size_t ws_size,
                              hipStream_t stream) {
    const float* features    = (const float*)d_in[0];
    const float* transitions = (const float*)d_in[1];
    const int*   seqlen      = (const int*)d_in[2];
    float* out = (float*)d_out;

    const size_t need = (size_t)TW + (size_t)BATCH * 64 * 4608;   // ~75.7 MB
    if (ws_size >= need) {
        crf_setup<<<1, 64, 0, stream>>>(transitions, seqlen, d_ws);
        crf_phase1c<<<4096, 256, 0, stream>>>(features, seqlen, d_ws);
        crf_phase2s<<<BATCH, 128, 0, stream>>>(transitions, seqlen, d_ws, out);
    } else {
        crf_scalar<<<BATCH, 64, 0, stream>>>(features, transitions, seqlen, out);
    }
}

// Round 19
// 120.012 us; speedup vs baseline: 2.0760x; 1.0081x over previous
//
#include <hip/hip_runtime.h>

#define BATCH 256
#define SEQ 2048
#define NT 48
#define START_TAG 46
#define END_TAG 47
#define LN2f  0.6931471805599453f

// ws layout
#define TAF16 0        // K16 A-frags exp(trans) bf16: [9][64] x 8B  = 4608
#define TBF   4608     // B-frag exp(trans) f32: [9][64] x 16B       = 9216
#define TCUM  13824    // prefix sums: int cum[257] (cum[0]=0)       = 1028
#define TSC   16384    // per-chunk log2 scales: [B][64] f32         = 64KiB
#define TW    131072   // chunk matrices bf16: [B][64][48][48]
                       //   chunk c < h : M row-major   (left half, b <- M b)
                       //   chunk c >= h: M^T row-major (right half, u^T <- u^T M)

typedef float v2f __attribute__((ext_vector_type(2)));
typedef float v4f __attribute__((ext_vector_type(4)));
typedef short s16x4 __attribute__((ext_vector_type(4)));
typedef unsigned int u32;
typedef unsigned short u16;
typedef u32 u32x2 __attribute__((ext_vector_type(2)));
typedef u32 u32x4 __attribute__((ext_vector_type(4)));

__device__ __forceinline__ u32 pkbf(float a, float b) {
    u32 r;
    asm("v_cvt_pk_bf16_f32 %0, %1, %2" : "=v"(r) : "v"(a), "v"(b));
    return r;
}
__device__ __forceinline__ float bflo(u32 w) { return __builtin_bit_cast(float, w << 16); }
__device__ __forceinline__ float bfhi(u32 w) { return __builtin_bit_cast(float, w & 0xffff0000u); }

__device__ __forceinline__ float rfl(float x) {
    return __builtin_bit_cast(float,
        __builtin_amdgcn_readfirstlane(__builtin_bit_cast(int, x)));
}

__device__ __forceinline__ v4f mfma16_z(s16x4 a, s16x4 b, v4f z) {
    v4f d;
    asm volatile("v_mfma_f32_16x16x16_bf16 %0, %2, %3, %1"
                 : "=&v"(d) : "v"(z), "v"(a), "v"(b));
    return d;
}
__device__ __forceinline__ void mfma16_acc(v4f& acc, s16x4 a, s16x4 b) {
    asm volatile("v_mfma_f32_16x16x16_bf16 %0, %1, %2, %0"
                 : "+v"(acc) : "v"(a), "v"(b));
}

// ---------------------------------------------------------------------------
// Kernel 0: exp(trans) fragments + chunk-count prefix sums (32-step chunks).
// ---------------------------------------------------------------------------
__global__ void __launch_bounds__(64)
crf_setup(const float* __restrict__ trans, const int* __restrict__ seqlen,
          void* ws) {
    __shared__ float el[NT * NT];
    const int lane = threadIdx.x, ln = lane & 15, g = lane >> 4;
    #pragma unroll
    for (int m = 0; m < 36; ++m) {
        int idx = lane + 64 * m;
        el[idx] = __expf(trans[idx]);
    }
    u32x2* AF = (u32x2*)((char*)ws + TAF16);
    v4f*   BF = (v4f*)((char*)ws + TBF);
    #pragma unroll
    for (int I = 0; I < 3; ++I)
        #pragma unroll
        for (int K = 0; K < 3; ++K) {
            const v4f ev = *(const v4f*)&el[(I * 16 + ln) * NT + K * 16 + g * 4];
            AF[(I * 3 + K) * 64 + lane] = (u32x2){pkbf(ev.x, ev.y), pkbf(ev.z, ev.w)};
        }
    #pragma unroll
    for (int K = 0; K < 3; ++K)
        #pragma unroll
        for (int J = 0; J < 3; ++J) {
            v4f v;
            #pragma unroll
            for (int i = 0; i < 4; ++i)
                v[i] = el[(K * 16 + g * 4 + i) * NT + J * 16 + ln];
            BF[(K * 3 + J) * 64 + lane] = v;
        }
    if (lane == 0) {
        int* cum = (int*)((char*)ws + TCUM);
        int acc = 0;
        for (int b = 0; b < BATCH; ++b) {
            cum[b] = acc;
            int L = seqlen[b];
            if (L < 1) L = 1;
            if (L > SEQ) L = SEQ;
            acc += (L + 31) >> 5;
        }
        cum[BATCH] = acc;
    }
}

// ---------------------------------------------------------------------------
// Kernel 1: wave widx handles the widx-th ACTIVE 32-step chunk (binary
// search over cum[]).  K16 MFMA chain (r13-proven): acc = E*M (27 MFMA,
// 3 levels x 9, asm-pinned), gn = raw P00, M' = acc .* (em * 1/gn_prev),
// Lc += log2(gn) lagged.  Emissions pre-exp'd into wave-private LDS.
// SINGLE-VARIABLE EXPERIMENT vs r18: __launch_bounds__(256,4) -> (256,5).
// Cap 512/5 = 102 — the untested point between clean-128 (occ 3/SIMD) and
// spilled-85/64 (r16/r14).  Body allocates 52 VGPR at cap 128, so 102
// leaves ~2x headroom; if the allocator stays clean, residency 3->5
// waves/SIMD.  LDS 24.6KB x 5 = 123KB <= 160KB.
// Pre-committed read: VGPR>=52 & FETCH~27MB = clean (expect phase1
// ~65-85us); VGPR<48 | FETCH>40MB = spill (revert next round, declare
// ceiling).
// ---------------------------------------------------------------------------
__global__ void __launch_bounds__(256, 5)
crf_phase1c(const float* __restrict__ feat, const int* __restrict__ seqlen,
            void* __restrict__ ws) {
    const int wid = threadIdx.x >> 6;
    const int widx = blockIdx.x * 4 + wid;
    const int* cum = (const int*)((const char*)ws + TCUM);
    if (widx >= cum[BATCH]) return;

    int lo = 0, hi = BATCH;          // invariant: cum[lo] <= widx < cum[hi]
    #pragma unroll
    for (int it = 0; it < 8; ++it) {
        int mid = (lo + hi) >> 1;
        if (cum[mid] <= widx) lo = mid; else hi = mid;
    }
    const int b = lo;
    const int c = widx - cum[b];
    const int t0 = c * 32;
    int Lraw = seqlen[b];
    if (Lraw < 1) Lraw = 1;
    if (Lraw > SEQ) Lraw = SEQ;
    const int nbS = (Lraw + 31) >> 5;
    const int half = nbS >> 1;
    int n = Lraw - t0;
    if (n > 32) n = 32;

    const int lane = threadIdx.x & 63, ln = lane & 15, g = lane >> 4;

    __shared__ v4f flv[4][32 * 12];
    v4f* fl = flv[wid];

    s16x4 aw[3][3];
    {
        const u32x2* AF = (const u32x2*)((const char*)ws + TAF16);
        #pragma unroll
        for (int I = 0; I < 3; ++I)
            #pragma unroll
            for (int K = 0; K < 3; ++K)
                aw[I][K] = __builtin_bit_cast(s16x4, AF[(I * 3 + K) * 64 + lane]);
    }

    // stage rows t0..t0+31 (t0 <= 2016, in-bounds), exp() applied once
    {
        const v4f* fg = (const v4f*)(feat + ((size_t)b * SEQ + t0) * NT);
        #pragma unroll
        for (int m = 0; m < 6; ++m) {
            v4f v = fg[m * 64 + lane];
            v4f e;
            #pragma unroll
            for (int i = 0; i < 4; ++i) e[i] = __expf(v[i]);
            fl[m * 64 + lane] = e;
        }
    }

    // init M = D_{t0} E
    s16x4 mw[3][3];
    {
        const v4f* BF = (const v4f*)((const char*)ws + TBF);
        v4f em[3];
        #pragma unroll
        for (int K = 0; K < 3; ++K) em[K] = fl[K * 4 + g];
        #pragma unroll
        for (int K = 0; K < 3; ++K)
            #pragma unroll
            for (int J = 0; J < 3; ++J) {
                v4f sc = BF[(K * 3 + J) * 64 + lane] * em[K];
                mw[K][J] = __builtin_bit_cast(s16x4,
                    (u32x2){pkbf(sc.x, sc.y), pkbf(sc.z, sc.w)});
            }
    }

    float Lc = 0.f, lg = 0.f, s = 1.f;
    const v4f kz = {0.f, 0.f, 0.f, 0.f};

    for (int t = 1; t < n; ++t) {
        v4f em[3];
        #pragma unroll
        for (int K = 0; K < 3; ++K) em[K] = fl[t * 12 + K * 4 + g];

        v4f acc[3][3];
        #pragma unroll
        for (int I = 0; I < 3; ++I)
            #pragma unroll
            for (int J = 0; J < 3; ++J)
                acc[I][J] = mfma16_z(aw[I][0], mw[0][J], kz);
        #pragma unroll
        for (int I = 0; I < 3; ++I)
            #pragma unroll
            for (int J = 0; J < 3; ++J)
                mfma16_acc(acc[I][J], aw[I][1], mw[1][J]);
        #pragma unroll
        for (int I = 0; I < 3; ++I)
            #pragma unroll
            for (int J = 0; J < 3; ++J)
                mfma16_acc(acc[I][J], aw[I][2], mw[2][J]);
        asm volatile("s_nop 7\n\ts_nop 7");
        __builtin_amdgcn_sched_barrier(0);

        const float gn = rfl(acc[0][0].x);
        Lc += lg;
        #pragma unroll
        for (int K = 0; K < 3; ++K) {
            v4f sp = em[K] * s;
            #pragma unroll
            for (int J = 0; J < 3; ++J) {
                v4f sc = acc[K][J] * sp;
                mw[K][J] = __builtin_bit_cast(s16x4,
                    (u32x2){pkbf(sc.x, sc.y), pkbf(sc.z, sc.w)});
            }
        }
        lg = __log2f(gn);
        s  = __builtin_amdgcn_rcpf(gn);
    }

    // store: element M[row][col], row = K*16+g*4+i, col = J*16+ln.
    char* wb = (char*)ws + TW + ((size_t)(b * 64 + c)) * 4608;
    if (c >= half) {
        // M^T row-major (right half): byte 2*(col*48+row)
        #pragma unroll
        for (int K = 0; K < 3; ++K)
            #pragma unroll
            for (int J = 0; J < 3; ++J) {
                u32x2 w = __builtin_bit_cast(u32x2, mw[K][J]);
                *(u32*)(wb + 2 * ((J * 16 + ln) * NT + K * 16 + g * 4))     = w.x;
                *(u32*)(wb + 2 * ((J * 16 + ln) * NT + K * 16 + g * 4 + 2)) = w.y;
            }
    } else {
        // M row-major (left half): byte 2*(row*48+col)
        u16* mb = (u16*)wb;
        #pragma unroll
        for (int K = 0; K < 3; ++K)
            #pragma unroll
            for (int J = 0; J < 3; ++J) {
                u32x2 w = __builtin_bit_cast(u32x2, mw[K][J]);
                const int r0 = K * 16 + g * 4, col = J * 16 + ln;
                mb[(r0 + 0) * NT + col] = (u16)(w.x & 0xffff);
                mb[(r0 + 1) * NT + col] = (u16)(w.x >> 16);
                mb[(r0 + 2) * NT + col] = (u16)(w.y & 0xffff);
                mb[(r0 + 3) * NT + col] = (u16)(w.y >> 16);
            }
    }
    if (lane == 0)
        ((float*)((char*)ws + TSC))[b * 64 + c] = Lc;
}

// ---------------------------------------------------------------------------
// Kernel 2 (split): 128 threads per sample.  Associativity:
//   out = u0^T (M_{nb-1}..M_h) (M_{h-1}..M_0) e_START
// wave0: a^T <- a^T M_c, c = nb-1..h   (M^T rows, a0 = exp(trans[END][:]))
// wave1: b   <- M_c b,   c = 0..h-1    (M rows,   b0 = e_START)
// Both rescale by first element per hop (guarded for b0[0]=0) and track D.
// out = ln2*(Da + Db + log2(a . b)).
// ---------------------------------------------------------------------------
__global__ void __launch_bounds__(128)
crf_phase2s(const float* __restrict__ trans, const int* __restrict__ seqlen,
            const void* __restrict__ ws, float* __restrict__ out) {
    const int b = blockIdx.x;
    const int wave = threadIdx.x >> 6;
    const int lane = threadIdx.x & 63;
    const int j = (lane < NT) ? lane : (lane - 16);

    __shared__ v4f hsv[2][12];
    __shared__ float sres[2][NT];
    __shared__ float sD[2];
    float* hs = (float*)hsv[wave];

    int L = seqlen[b];
    if (L < 1) L = 1;
    if (L > SEQ) L = SEQ;
    const int nb = (L + 31) >> 5;
    const int half = nb >> 1;
    const float* sc = (const float*)((const char*)ws + TSC) + b * 64;
    const char* wbase = (const char*)ws + TW + (size_t)b * 64 * 4608;

    // per-wave chunk range and direction
    const int c0   = wave ? 0 : (nb - 1);      // first chunk
    const int cstep = wave ? 1 : -1;
    const int nhops = wave ? half : (nb - half);

    float q = wave ? ((j == START_TAG) ? 1.f : 0.f)
                   : __expf(trans[END_TAG * NT + j]);
    float D = 0.f;

    if (nhops > 0) {
        u32x4 buf[6];
        {
            const u32x4* wr = (const u32x4*)(wbase + (size_t)c0 * 4608 + j * 96);
            #pragma unroll
            for (int m = 0; m < 6; ++m) buf[m] = wr[m];
        }
        for (int hh = 0; hh < nhops; ++hh) {
            const int c = c0 + hh * cstep;
            u32x4 cur[6];
            #pragma unroll
            for (int m = 0; m < 6; ++m) cur[m] = buf[m];
            if (hh + 1 < nhops) {
                const u32x4* wr =
                    (const u32x4*)(wbase + (size_t)(c + cstep) * 4608 + j * 96);
                #pragma unroll
                for (int m = 0; m < 6; ++m) buf[m] = wr[m];
            }

            if (lane < NT) hs[lane] = q;
            v4f hq[12];
            #pragma unroll
            for (int k = 0; k < 12; ++k) hq[k] = hsv[wave][k];
            const float h0 = hq[0][0];

            v2f a = {0.f, 0.f};
            #pragma unroll
            for (int m = 0; m < 6; ++m) {
                #pragma unroll
                for (int p = 0; p < 4; ++p) {
                    const int i = 2 * (4 * m + p);
                    u32 wv = cur[m][p];
                    v2f wp;
                    wp.x = bflo(wv);
                    wp.y = bfhi(wv);
                    v2f up = { hq[i >> 2][i & 3], hq[i >> 2][(i & 3) + 1] };
                    a += wp * up;
                }
            }
            const float dot = a.x + a.y;
            const bool ok = (h0 > 0.f);
            q = ok ? dot * __builtin_amdgcn_rcpf(h0) : dot;
            D += (ok ? __log2f(h0) : 0.f) + sc[c];
        }
    }

    if (lane < NT) sres[wave][j] = q;
    if (lane == 0) sD[wave] = D;
    __syncthreads();

    if (wave == 0) {
        float term = (lane < NT) ? sres[0][lane] * sres[1][lane] : 0.f;
        #pragma unroll
        for (int m = 32; m >= 1; m >>= 1) term += __shfl_xor(term, m, 64);
        if (lane == 0)
            out[b] = LN2f * (sD[0] + sD[1] + __log2f(term));
    }
}

// ---------------------------------------------------------------------------
// Fallback: proven round-2 scalar kernel (ws too small)
// ---------------------------------------------------------------------------
__global__ void __launch_bounds__(64)
crf_scalar(const float* __restrict__ features, const float* __restrict__ transitions,
           const int* __restrict__ seq_len, float* __restrict__ out) {
    const int b = blockIdx.x;
    const int lane = threadIdx.x;
    const int j = (lane < NT) ? lane : (lane - 16);
    __shared__ v4f hs4[NT / 4];
    float* hs = (float*)hs4;

    v2f E2[NT / 2];
    {
        const v4f* trow = (const v4f*)(transitions + j * NT);
        #pragma unroll
        for (int k = 0; k < NT / 4; ++k) {
            v4f tv = trow[k];
            E2[2 * k].x = __expf(tv.x); E2[2 * k].y = __expf(tv.y);
            E2[2 * k + 1].x = __expf(tv.z); E2[2 * k + 1].y = __expf(tv.w);
        }
    }
    const float Eend = __expf(transitions[END_TAG * NT + j]);
    const int L = seq_len[b];
    const float* fbase = features + ((size_t)b * SEQ) * NT + j;

    float q = E2[START_TAG / 2].x * __expf(fbase[0]);
    float Clog2 = 0.0f;
    if (lane < NT) hs[lane] = q;

    float fb[8];
    #pragma unroll
    for (int u = 0; u < 8; ++u) {
        int tp = 1 + u;
        fb[u] = fbase[(size_t)(tp < SEQ ? tp : 0) * NT];
    }

    auto STEP = [&](float femit) {
        v4f hq[NT / 4];
        #pragma unroll
        for (int k = 0; k < NT / 4; ++k) hq[k] = hs4[k];
        float h0 = hq[0].x;
        float r = __builtin_amdgcn_rcpf(h0);
        float e = __expf(femit);
        float re = r * e;
        v2f a0 = {0.f, 0.f}, a1 = {0.f, 0.f};
        #pragma unroll
        for (int k = 0; k < NT / 4; ++k) {
            v2f lo = { hq[k].x, hq[k].y };
            v2f hi = { hq[k].z, hq[k].w };
            a0 += E2[2 * k] * lo;
            a1 += E2[2 * k + 1] * hi;
        }
        float d = (a0.x + a1.x) + (a0.y + a1.y);
        q = d * re;
        Clog2 += __log2f(h0);
        if (lane < NT) hs[lane] = q;
    };

    int t = 1;
    while (t + 8 <= L) {
        #pragma unroll
        for (int u = 0; u < 8; ++u) {
            STEP(fb[u]);
            int tp = t + u + 8;
            fb[u] = fbase[(size_t)(tp < SEQ ? tp : 0) * NT];
        }
        t += 8;
    }
    #pragma unroll
    for (int u = 0; u < 8; ++u)
        if (t + u < L) STEP(fb[u]);

    float term = (lane < NT) ? q * Eend : 0.0f;
    #pragma unroll
    for (int m = 32; m >= 1; m >>= 1) term += __shfl_xor(term, m, 64);
    if (lane == 0) out[b] = LN2f * (Clog2 + __log2f(term));
}

extern "C" void kernel_launch(void* const* d_in, const int* in_sizes, int n_in,
                              void* d_out, int out_size, void* d_ws, size_t ws_size,
                              hipStream_t stream) {
    const float* features    = (const float*)d_in[0];
    const float* transitions = (const float*)d_in[1];
    const int*   seqlen      = (const int*)d_in[2];
    float* out = (float*)d_out;

    const size_t need = (size_t)TW + (size_t)BATCH * 64 * 4608;   // ~75.7 MB
    if (ws_size >= need) {
        crf_setup<<<1, 64, 0, stream>>>(transitions, seqlen, d_ws);
        crf_phase1c<<<4096, 256, 0, stream>>>(features, seqlen, d_ws);
        crf_phase2s<<<BATCH, 128, 0, stream>>>(transitions, seqlen, d_ws, out);
    } else {
        crf_scalar<<<BATCH, 64, 0, stream>>>(features, transitions, seqlen, out);
    }
}